// Round 1
// baseline (1014.567 us; speedup 1.0000x reference)
//
#include <hip/hip_runtime.h>
#include <cstdint>

// SelfAttention fused pipeline, bf16 MFMA path.
// B=2 S=2048 DIM=4096 HQ=32 HKV=8 D=128, causal, start_pos=0.
//
// ws layout (bytes):
//   xb    @ 0         : bf16[4096][4096]   x cast               (33.5 MB)
//   wt    @ 33554432  : bf16[6144][4096]   [wq^T*scale; wk^T; wv^T] (50.3 MB)
//   wot   @ 83886080  : bf16[4096][4096]   wo^T                 (33.5 MB)
//   qkv   @ 117440512 : bf16[4096][6144]   x@[wq wk wv]         (50.3 MB)
//   vt    @ 167772160 : bf16[2][8][128][2048] V^T per kv head   (8.4 MB)
//   ao    @ 176160768 : bf16[4096][4096]   attention output     (33.5 MB)
// total 209715200 bytes.

typedef __bf16 bf16;
typedef __bf16 bf16x8 __attribute__((ext_vector_type(8)));
typedef float f32x4 __attribute__((ext_vector_type(4)));

#define DEV_INLINE __device__ __forceinline__

DEV_INLINE void load_lds16(const bf16* g, bf16* l) {
  // async global->LDS, 16B per lane; LDS dest = wave-uniform base + lane*16
  __builtin_amdgcn_global_load_lds(
      (const __attribute__((address_space(1))) void*)g,
      (__attribute__((address_space(3))) void*)l, 16, 0, 0);
}

// ---------------- elementwise cast f32 -> bf16, 8 elems/thread ----------------
__global__ __launch_bounds__(256) void cast_f32_bf16(const float* __restrict__ in,
                                                     bf16* __restrict__ out, int n) {
  int i = (blockIdx.x * 256 + threadIdx.x) * 8;
  if (i >= n) return;
  float4 a = *(const float4*)(in + i);
  float4 b = *(const float4*)(in + i + 4);
  bf16x8 o;
  o[0] = (bf16)a.x; o[1] = (bf16)a.y; o[2] = (bf16)a.z; o[3] = (bf16)a.w;
  o[4] = (bf16)b.x; o[5] = (bf16)b.y; o[6] = (bf16)b.z; o[7] = (bf16)b.w;
  *(bf16x8*)(out + i) = o;
}

// ------------- transpose+cast: f32 in[K][N] -> bf16 out[N][K] * scale ---------
__global__ __launch_bounds__(256) void transpose_cast_w(const float* __restrict__ in,
                                                        bf16* __restrict__ out,
                                                        int K, int N, float scale) {
  __shared__ float t[32][33];
  int n0 = blockIdx.x * 32, k0 = blockIdx.y * 32;
  int tx = threadIdx.x, ty = threadIdx.y;
#pragma unroll
  for (int i = 0; i < 32; i += 8)
    t[ty + i][tx] = in[(size_t)(k0 + ty + i) * N + n0 + tx];
  __syncthreads();
#pragma unroll
  for (int i = 0; i < 32; i += 8)
    out[(size_t)(n0 + ty + i) * K + k0 + tx] = (bf16)(t[tx][ty + i] * scale);
}

// ------ transpose V slice of qkv[4096][6144] -> vt[(b*8+h)*128 + d][2048] -----
__global__ __launch_bounds__(256) void transpose_v(const bf16* __restrict__ qkv,
                                                   bf16* __restrict__ vt) {
  __shared__ bf16 t[32][33];
  int s0 = blockIdx.x * 32, d0 = blockIdx.y * 32, bh = blockIdx.z;
  int b = bh >> 3, h = bh & 7;
  int tx = threadIdx.x, ty = threadIdx.y;
#pragma unroll
  for (int i = 0; i < 32; i += 8)
    t[ty + i][tx] =
        qkv[(size_t)(b * 2048 + s0 + ty + i) * 6144 + 5120 + h * 128 + d0 + tx];
  __syncthreads();
#pragma unroll
  for (int i = 0; i < 32; i += 8)
    vt[((size_t)bh * 128 + d0 + ty + i) * 2048 + s0 + tx] = t[tx][ty + i];
}

// --------- m97-style GEMM: C[M][N] = A[M][K] * Bt[N][K]^T, bf16 MFMA ---------
template <typename OT>
__global__ __launch_bounds__(256, 2) void gemm_bt(const bf16* __restrict__ A,
                                                  const bf16* __restrict__ Bt,
                                                  OT* __restrict__ C,
                                                  int M, int N, int K) {
  __shared__ __align__(16) bf16 As[128 * 32];
  __shared__ __align__(16) bf16 Bs[128 * 32];
  const int t = threadIdx.x, w = t >> 6, l = t & 63;
  const int lr = l & 15, lh = l >> 4;
  const int mBase = blockIdx.y * 128, nBase = blockIdx.x * 128;
  const int wm = (w >> 1) * 64, wn = (w & 1) * 64;
  f32x4 acc[4][4] = {};
  for (int k0 = 0; k0 < K; k0 += 32) {
#pragma unroll
    for (int p = 0; p < 2; p++) {
      int c = p * 256 + t;           // 16B chunk id, 512 chunks per 8KB tile
      int row = c >> 2, kq = c & 3;
      int ldsoff = (p * 256 + w * 64) * 8;  // elements; hw adds lane*16B
      load_lds16(A + (size_t)(mBase + row) * K + k0 + kq * 8, &As[ldsoff]);
      load_lds16(Bt + (size_t)(nBase + row) * K + k0 + kq * 8, &Bs[ldsoff]);
    }
    __syncthreads();
    bf16x8 a[4], b[4];
#pragma unroll
    for (int mi = 0; mi < 4; mi++)
      a[mi] = *(const bf16x8*)&As[(wm + mi * 16 + lr) * 32 + lh * 8];
#pragma unroll
    for (int ni = 0; ni < 4; ni++)
      b[ni] = *(const bf16x8*)&Bs[(wn + ni * 16 + lr) * 32 + lh * 8];
#pragma unroll
    for (int mi = 0; mi < 4; mi++)
#pragma unroll
      for (int ni = 0; ni < 4; ni++)
        acc[mi][ni] = __builtin_amdgcn_mfma_f32_16x16x32_bf16(a[mi], b[ni],
                                                              acc[mi][ni], 0, 0, 0);
    __syncthreads();
  }
#pragma unroll
  for (int mi = 0; mi < 4; mi++)
#pragma unroll
    for (int ni = 0; ni < 4; ni++) {
      int row = mBase + wm + mi * 16 + lh * 4;
      int col = nBase + wn + ni * 16 + lr;
#pragma unroll
      for (int r = 0; r < 4; r++)
        C[(size_t)(row + r) * N + col] = (OT)acc[mi][ni][r];
    }
}

// ------------------------------ flash attention ------------------------------
// grid (qt=16, h=32, b=2), block 256. Wave w handles q rows [qt*128+w*32, +32).
// KTILE=64. Ks[k][d], Vts[d][kpos], Ps per-wave [32][72] (pad 4 -> 144B rows).
__global__ __launch_bounds__(256, 2) void flash_attn(const bf16* __restrict__ qkv,
                                                     const bf16* __restrict__ vt,
                                                     bf16* __restrict__ ao) {
  __shared__ __align__(16) bf16 Ks[64 * 128];
  __shared__ __align__(16) bf16 Vts[128 * 64];
  __shared__ __align__(16) bf16 Ps[4][32 * 72];
  const int t = threadIdx.x, w = t >> 6, l = t & 63;
  const int lr = l & 15, lh = l >> 4;
  const int qt = blockIdx.x, h = blockIdx.y, b = blockIdx.z;
  const int hkv = h >> 2;                 // jnp.repeat: q head h <- kv head h/4
  const int qrow0 = qt * 128 + w * 32;

  // Q fragments (A-operand): q = qrow0 + rt*16 + lr, d = ds*32 + lh*8 + j.
  // 1/sqrt(128) already folded into wq.
  bf16x8 qf[2][4];
#pragma unroll
  for (int rt = 0; rt < 2; rt++)
#pragma unroll
    for (int ds = 0; ds < 4; ds++)
      qf[rt][ds] = *(const bf16x8*)&qkv[(size_t)(b * 2048 + qrow0 + rt * 16 + lr) * 6144 +
                                        h * 128 + ds * 32 + lh * 8];

  f32x4 oacc[2][8] = {};
  float mrow[2][4], lsum[2][4];
#pragma unroll
  for (int rt = 0; rt < 2; rt++)
#pragma unroll
    for (int r = 0; r < 4; r++) { mrow[rt][r] = -3.0e38f; lsum[rt][r] = 0.f; }

  const float LOG2E = 1.4426950408889634f;
  const int nkt = 2 * qt + 2;
  for (int kt = 0; kt < nkt; kt++) {
    const int kbase = kt * 64;
    __syncthreads();  // prior iteration's LDS reads complete before restage
#pragma unroll
    for (int p = 0; p < 4; p++) {
      int c = p * 256 + t;
      int ldsoff = (p * 256 + w * 64) * 8;
      // Ks: row = k (c>>4), 16 chunks per 128-d row
      load_lds16(qkv + (size_t)(b * 2048 + kbase + (c >> 4)) * 6144 + 4096 +
                     hkv * 128 + (c & 15) * 8,
                 &Ks[ldsoff]);
      // Vts: row = d (c>>3), 8 chunks per 64-kpos row
      load_lds16(vt + ((size_t)(b * 8 + hkv) * 128 + (c >> 3)) * 2048 + kbase +
                     (c & 7) * 8,
                 &Vts[ldsoff]);
    }
    __syncthreads();

    // S = Q K^T  (C/D layout: row = rt*16 + lh*4 + r, col = ct*16 + lr)
    f32x4 s[2][4];
#pragma unroll
    for (int ct = 0; ct < 4; ct++) {
      bf16x8 kf[4];
#pragma unroll
      for (int ds = 0; ds < 4; ds++)
        kf[ds] = *(const bf16x8*)&Ks[(ct * 16 + lr) * 128 + ds * 32 + lh * 8];
#pragma unroll
      for (int rt = 0; rt < 2; rt++) {
        f32x4 acc = {0.f, 0.f, 0.f, 0.f};
#pragma unroll
        for (int ds = 0; ds < 4; ds++)
          acc = __builtin_amdgcn_mfma_f32_16x16x32_bf16(qf[rt][ds], kf[ds], acc, 0, 0, 0);
        s[rt][ct] = acc;
      }
    }

    if (kt >= 2 * qt) {  // diagonal tiles only
#pragma unroll
      for (int rt = 0; rt < 2; rt++)
#pragma unroll
        for (int ct = 0; ct < 4; ct++)
#pragma unroll
          for (int r = 0; r < 4; r++) {
            int qi = qrow0 + rt * 16 + lh * 4 + r;
            int ki = kbase + ct * 16 + lr;
            if (ki > qi) s[rt][ct][r] = -3.0e38f;
          }
    }

    // online softmax (base-2 domain), rows per lane: (rt, r), 16-lane groups
    float alpha[2][4];
#pragma unroll
    for (int rt = 0; rt < 2; rt++)
#pragma unroll
      for (int r = 0; r < 4; r++) {
        float mx = fmaxf(fmaxf(s[rt][0][r], s[rt][1][r]),
                         fmaxf(s[rt][2][r], s[rt][3][r]));
        mx = fmaxf(mx, __shfl_xor(mx, 1));
        mx = fmaxf(mx, __shfl_xor(mx, 2));
        mx = fmaxf(mx, __shfl_xor(mx, 4));
        mx = fmaxf(mx, __shfl_xor(mx, 8));
        float mnew = fmaxf(mrow[rt][r], mx);
        float al = exp2f((mrow[rt][r] - mnew) * LOG2E);
        mrow[rt][r] = mnew;
        alpha[rt][r] = al;
        float rs = 0.f;
#pragma unroll
        for (int ct = 0; ct < 4; ct++) {
          float p = exp2f((s[rt][ct][r] - mnew) * LOG2E);
          s[rt][ct][r] = p;
          rs += p;
        }
        rs += __shfl_xor(rs, 1);
        rs += __shfl_xor(rs, 2);
        rs += __shfl_xor(rs, 4);
        rs += __shfl_xor(rs, 8);
        lsum[rt][r] = lsum[rt][r] * al + rs;
      }

    // rescale O accumulator
#pragma unroll
    for (int rt = 0; rt < 2; rt++)
#pragma unroll
      for (int dt = 0; dt < 8; dt++)
#pragma unroll
        for (int r = 0; r < 4; r++) oacc[rt][dt][r] *= alpha[rt][r];

    // P: C-layout regs -> LDS -> A-operand fragments (m120 pattern)
#pragma unroll
    for (int rt = 0; rt < 2; rt++)
#pragma unroll
      for (int ct = 0; ct < 4; ct++)
#pragma unroll
        for (int r = 0; r < 4; r++)
          Ps[w][(rt * 16 + lh * 4 + r) * 72 + ct * 16 + lr] = (bf16)s[rt][ct][r];
    bf16x8 pf[2][2];
#pragma unroll
    for (int rt = 0; rt < 2; rt++)
#pragma unroll
      for (int ks = 0; ks < 2; ks++)
        pf[rt][ks] = *(const bf16x8*)&Ps[w][(rt * 16 + lr) * 72 + ks * 32 + lh * 8];

    // O += P V  (B-operand from Vts: row = d, k-contiguous kpos)
#pragma unroll
    for (int dt = 0; dt < 8; dt++)
#pragma unroll
      for (int ks = 0; ks < 2; ks++) {
        bf16x8 vf = *(const bf16x8*)&Vts[(dt * 16 + lr) * 64 + ks * 32 + lh * 8];
#pragma unroll
        for (int rt = 0; rt < 2; rt++)
          oacc[rt][dt] =
              __builtin_amdgcn_mfma_f32_16x16x32_bf16(pf[rt][ks], vf, oacc[rt][dt], 0, 0, 0);
      }
  }

  // epilogue: normalize and store
#pragma unroll
  for (int rt = 0; rt < 2; rt++)
#pragma unroll
    for (int dt = 0; dt < 8; dt++)
#pragma unroll
      for (int r = 0; r < 4; r++) {
        float o = oacc[rt][dt][r] / lsum[rt][r];
        int row = b * 2048 + qrow0 + rt * 16 + lh * 4 + r;
        int col = h * 128 + dt * 16 + lr;
        ao[(size_t)row * 4096 + col] = (bf16)o;
      }
}

extern "C" void kernel_launch(void* const* d_in, const int* in_sizes, int n_in,
                              void* d_out, int out_size, void* d_ws, size_t ws_size,
                              hipStream_t stream) {
  const float* x = (const float*)d_in[0];
  const float* wq = (const float*)d_in[1];
  const float* wk = (const float*)d_in[2];
  const float* wv = (const float*)d_in[3];
  const float* wo = (const float*)d_in[4];
  float* out = (float*)d_out;

  char* ws = (char*)d_ws;
  bf16* xb = (bf16*)(ws + 0);
  bf16* wt = (bf16*)(ws + 33554432);       // [6144][4096]: wq^T | wk^T | wv^T
  bf16* wot = (bf16*)(ws + 83886080);      // [4096][4096]
  bf16* qkv = (bf16*)(ws + 117440512);     // [4096][6144]
  bf16* vt = (bf16*)(ws + 167772160);      // [16][128][2048]
  bf16* ao = (bf16*)(ws + 176160768);      // [4096][4096]
  if (ws_size < 209715200u) return;        // need ~210MB scratch

  const float qscale = 0.08838834764831845f;  // 1/sqrt(128), folded into wq

  cast_f32_bf16<<<8192, 256, 0, stream>>>(x, xb, 16777216);
  dim3 tb(32, 8);
  transpose_cast_w<<<dim3(128, 128), tb, 0, stream>>>(wq, wt, 4096, 4096, qscale);
  transpose_cast_w<<<dim3(32, 128), tb, 0, stream>>>(wk, wt + (size_t)4096 * 4096,
                                                     4096, 1024, 1.0f);
  transpose_cast_w<<<dim3(32, 128), tb, 0, stream>>>(wv, wt + (size_t)5120 * 4096,
                                                     4096, 1024, 1.0f);
  transpose_cast_w<<<dim3(128, 128), tb, 0, stream>>>(wo, wot, 4096, 4096, 1.0f);

  gemm_bt<bf16><<<dim3(48, 32), 256, 0, stream>>>(xb, wt, qkv, 4096, 6144, 4096);
  transpose_v<<<dim3(64, 4, 16), tb, 0, stream>>>(qkv, vt);
  flash_attn<<<dim3(16, 32, 2), 256, 0, stream>>>(qkv, vt, ao);
  gemm_bt<float><<<dim3(32, 32), 256, 0, stream>>>(ao, wot, out, 4096, 4096, 4096);
}

// Round 2
// 816.367 us; speedup vs baseline: 1.2428x; 1.2428x over previous
//
#include <hip/hip_runtime.h>
#include <cstdint>

// SelfAttention fused pipeline, bf16 MFMA path.
// B=2 S=2048 DIM=4096 HQ=32 HKV=8 D=128, causal, start_pos=0.
//
// R1 changes (flash_attn only):
//  - XOR-swizzle Ks/Vts 16B-chunk placement (DMA source side) to kill the
//    16-way LDS bank conflicts on row-strided ds_read_b128 (row strides 256B/
//    128B alias all rows to one bank quad; swizzle spreads -> 2-way = free).
//  - Pair q-tiles (a, 15-a) per block: uniform 34 k-tiles/block, grid 512.
//  - Fold log2(e) into q scale: softmax natively in base-2 domain.
//
// ws layout (bytes):
//   xb    @ 0         : bf16[4096][4096]   x cast               (33.5 MB)
//   wt    @ 33554432  : bf16[6144][4096]   [wq^T*scale; wk^T; wv^T] (50.3 MB)
//   wot   @ 83886080  : bf16[4096][4096]   wo^T                 (33.5 MB)
//   qkv   @ 117440512 : bf16[4096][6144]   x@[wq wk wv]         (50.3 MB)
//   vt    @ 167772160 : bf16[2][8][128][2048] V^T per kv head   (8.4 MB)
//   ao    @ 176160768 : bf16[4096][4096]   attention output     (33.5 MB)
// total 209715200 bytes.

typedef __bf16 bf16;
typedef __bf16 bf16x8 __attribute__((ext_vector_type(8)));
typedef float f32x4 __attribute__((ext_vector_type(4)));

#define DEV_INLINE __device__ __forceinline__

DEV_INLINE void load_lds16(const bf16* g, bf16* l) {
  // async global->LDS, 16B per lane; LDS dest = wave-uniform base + lane*16
  __builtin_amdgcn_global_load_lds(
      (const __attribute__((address_space(1))) void*)g,
      (__attribute__((address_space(3))) void*)l, 16, 0, 0);
}

// ---------------- elementwise cast f32 -> bf16, 8 elems/thread ----------------
__global__ __launch_bounds__(256) void cast_f32_bf16(const float* __restrict__ in,
                                                     bf16* __restrict__ out, int n) {
  int i = (blockIdx.x * 256 + threadIdx.x) * 8;
  if (i >= n) return;
  float4 a = *(const float4*)(in + i);
  float4 b = *(const float4*)(in + i + 4);
  bf16x8 o;
  o[0] = (bf16)a.x; o[1] = (bf16)a.y; o[2] = (bf16)a.z; o[3] = (bf16)a.w;
  o[4] = (bf16)b.x; o[5] = (bf16)b.y; o[6] = (bf16)b.z; o[7] = (bf16)b.w;
  *(bf16x8*)(out + i) = o;
}

// ------------- transpose+cast: f32 in[K][N] -> bf16 out[N][K] * scale ---------
__global__ __launch_bounds__(256) void transpose_cast_w(const float* __restrict__ in,
                                                        bf16* __restrict__ out,
                                                        int K, int N, float scale) {
  __shared__ float t[32][33];
  int n0 = blockIdx.x * 32, k0 = blockIdx.y * 32;
  int tx = threadIdx.x, ty = threadIdx.y;
#pragma unroll
  for (int i = 0; i < 32; i += 8)
    t[ty + i][tx] = in[(size_t)(k0 + ty + i) * N + n0 + tx];
  __syncthreads();
#pragma unroll
  for (int i = 0; i < 32; i += 8)
    out[(size_t)(n0 + ty + i) * K + k0 + tx] = (bf16)(t[tx][ty + i] * scale);
}

// ------ transpose V slice of qkv[4096][6144] -> vt[(b*8+h)*128 + d][2048] -----
__global__ __launch_bounds__(256) void transpose_v(const bf16* __restrict__ qkv,
                                                   bf16* __restrict__ vt) {
  __shared__ bf16 t[32][33];
  int s0 = blockIdx.x * 32, d0 = blockIdx.y * 32, bh = blockIdx.z;
  int b = bh >> 3, h = bh & 7;
  int tx = threadIdx.x, ty = threadIdx.y;
#pragma unroll
  for (int i = 0; i < 32; i += 8)
    t[ty + i][tx] =
        qkv[(size_t)(b * 2048 + s0 + ty + i) * 6144 + 5120 + h * 128 + d0 + tx];
  __syncthreads();
#pragma unroll
  for (int i = 0; i < 32; i += 8)
    vt[((size_t)bh * 128 + d0 + ty + i) * 2048 + s0 + tx] = t[tx][ty + i];
}

// --------- m97-style GEMM: C[M][N] = A[M][K] * Bt[N][K]^T, bf16 MFMA ---------
template <typename OT>
__global__ __launch_bounds__(256, 2) void gemm_bt(const bf16* __restrict__ A,
                                                  const bf16* __restrict__ Bt,
                                                  OT* __restrict__ C,
                                                  int M, int N, int K) {
  __shared__ __align__(16) bf16 As[128 * 32];
  __shared__ __align__(16) bf16 Bs[128 * 32];
  const int t = threadIdx.x, w = t >> 6, l = t & 63;
  const int lr = l & 15, lh = l >> 4;
  const int mBase = blockIdx.y * 128, nBase = blockIdx.x * 128;
  const int wm = (w >> 1) * 64, wn = (w & 1) * 64;
  f32x4 acc[4][4] = {};
  for (int k0 = 0; k0 < K; k0 += 32) {
#pragma unroll
    for (int p = 0; p < 2; p++) {
      int c = p * 256 + t;           // 16B chunk id, 512 chunks per 8KB tile
      int row = c >> 2, kq = c & 3;
      int ldsoff = (p * 256 + w * 64) * 8;  // elements; hw adds lane*16B
      load_lds16(A + (size_t)(mBase + row) * K + k0 + kq * 8, &As[ldsoff]);
      load_lds16(Bt + (size_t)(nBase + row) * K + k0 + kq * 8, &Bs[ldsoff]);
    }
    __syncthreads();
    bf16x8 a[4], b[4];
#pragma unroll
    for (int mi = 0; mi < 4; mi++)
      a[mi] = *(const bf16x8*)&As[(wm + mi * 16 + lr) * 32 + lh * 8];
#pragma unroll
    for (int ni = 0; ni < 4; ni++)
      b[ni] = *(const bf16x8*)&Bs[(wn + ni * 16 + lr) * 32 + lh * 8];
#pragma unroll
    for (int mi = 0; mi < 4; mi++)
#pragma unroll
      for (int ni = 0; ni < 4; ni++)
        acc[mi][ni] = __builtin_amdgcn_mfma_f32_16x16x32_bf16(a[mi], b[ni],
                                                              acc[mi][ni], 0, 0, 0);
    __syncthreads();
  }
#pragma unroll
  for (int mi = 0; mi < 4; mi++)
#pragma unroll
    for (int ni = 0; ni < 4; ni++) {
      int row = mBase + wm + mi * 16 + lh * 4;
      int col = nBase + wn + ni * 16 + lr;
#pragma unroll
      for (int r = 0; r < 4; r++)
        C[(size_t)(row + r) * N + col] = (OT)acc[mi][ni][r];
    }
}

// ------------------------------ flash attention ------------------------------
// grid (8, h=32, b=2), block 256. Block handles q-tiles blockIdx.x and
// 15-blockIdx.x -> uniform 34 k-tiles/block. Wave w: q rows [qt*128+w*32,+32).
// KTILE=64. Ks[k][d] / Vts[d][kpos] stored with XOR-swizzled 16B chunks:
//   Ks  chunk(k, j)  at physical chunk k*16 + (j ^ (k & 15))   (16 chunks/row)
//   Vts chunk(d, j)  at physical chunk d*8  + (j ^ (d & 7))    (8 chunks/row)
// -> row-strided b128 reads spread over all bank quads (2-way max = free).
// Softmax in base-2 domain (log2e folded into wq scale).
__global__ __launch_bounds__(256, 2) void flash_attn(const bf16* __restrict__ qkv,
                                                     const bf16* __restrict__ vt,
                                                     bf16* __restrict__ ao) {
  __shared__ __align__(16) bf16 Ks[64 * 128];
  __shared__ __align__(16) bf16 Vts[128 * 64];
  __shared__ __align__(16) bf16 Ps[4][32 * 72];
  const int t = threadIdx.x, w = t >> 6, l = t & 63;
  const int lr = l & 15, lh = l >> 4;
  const int h = blockIdx.y, b = blockIdx.z;
  const int hkv = h >> 2;                 // jnp.repeat: q head h <- kv head h/4

  for (int phase = 0; phase < 2; phase++) {
    const int qt = phase == 0 ? blockIdx.x : 15 - blockIdx.x;
    const int qrow0 = qt * 128 + w * 32;

    // Q fragments (A-operand): q = qrow0 + rt*16 + lr, d = ds*32 + lh*8 + j.
    // log2(e)/sqrt(128) already folded into wq.
    bf16x8 qf[2][4];
#pragma unroll
    for (int rt = 0; rt < 2; rt++)
#pragma unroll
      for (int ds = 0; ds < 4; ds++)
        qf[rt][ds] = *(const bf16x8*)&qkv[(size_t)(b * 2048 + qrow0 + rt * 16 + lr) * 6144 +
                                          h * 128 + ds * 32 + lh * 8];

    f32x4 oacc[2][8] = {};
    float mrow[2][4], lsum[2][4];
#pragma unroll
    for (int rt = 0; rt < 2; rt++)
#pragma unroll
      for (int r = 0; r < 4; r++) { mrow[rt][r] = -3.0e38f; lsum[rt][r] = 0.f; }

    const int nkt = 2 * qt + 2;
    for (int kt = 0; kt < nkt; kt++) {
      const int kbase = kt * 64;
      __syncthreads();  // prior iteration's (or phase's) LDS reads complete
#pragma unroll
      for (int p = 0; p < 4; p++) {
        int c = p * 256 + t;
        int ldsoff = (p * 256 + w * 64) * 8;
        // Ks: physical chunk c holds logical chunk (c&15)^(krow&15) of row c>>4
        int krow = c >> 4, kj = (c & 15) ^ (krow & 15);
        load_lds16(qkv + (size_t)(b * 2048 + kbase + krow) * 6144 + 4096 +
                       hkv * 128 + kj * 8,
                   &Ks[ldsoff]);
        // Vts: physical chunk c holds logical chunk (c&7)^(vrow&7) of row c>>3
        int vrow = c >> 3, vj = (c & 7) ^ (vrow & 7);
        load_lds16(vt + ((size_t)(b * 8 + hkv) * 128 + vrow) * 2048 + kbase +
                       vj * 8,
                   &Vts[ldsoff]);
      }
      __syncthreads();

      // S = Q K^T  (C/D layout: row = rt*16 + lh*4 + r, col = ct*16 + lr)
      f32x4 s[2][4];
#pragma unroll
      for (int ct = 0; ct < 4; ct++) {
        bf16x8 kf[4];
#pragma unroll
        for (int ds = 0; ds < 4; ds++)
          kf[ds] = *(const bf16x8*)&Ks[((ct * 16 + lr) * 16 + ((ds * 4 + lh) ^ lr)) * 8];
#pragma unroll
        for (int rt = 0; rt < 2; rt++) {
          f32x4 acc = {0.f, 0.f, 0.f, 0.f};
#pragma unroll
          for (int ds = 0; ds < 4; ds++)
            acc = __builtin_amdgcn_mfma_f32_16x16x32_bf16(qf[rt][ds], kf[ds], acc, 0, 0, 0);
          s[rt][ct] = acc;
        }
      }

      if (kt >= 2 * qt) {  // diagonal tiles only
#pragma unroll
        for (int rt = 0; rt < 2; rt++)
#pragma unroll
          for (int ct = 0; ct < 4; ct++)
#pragma unroll
            for (int r = 0; r < 4; r++) {
              int qi = qrow0 + rt * 16 + lh * 4 + r;
              int ki = kbase + ct * 16 + lr;
              if (ki > qi) s[rt][ct][r] = -3.0e38f;
            }
      }

      // online softmax (base-2 domain), rows per lane: (rt, r), 16-lane groups
      float alpha[2][4];
#pragma unroll
      for (int rt = 0; rt < 2; rt++)
#pragma unroll
        for (int r = 0; r < 4; r++) {
          float mx = fmaxf(fmaxf(s[rt][0][r], s[rt][1][r]),
                           fmaxf(s[rt][2][r], s[rt][3][r]));
          mx = fmaxf(mx, __shfl_xor(mx, 1));
          mx = fmaxf(mx, __shfl_xor(mx, 2));
          mx = fmaxf(mx, __shfl_xor(mx, 4));
          mx = fmaxf(mx, __shfl_xor(mx, 8));
          float mnew = fmaxf(mrow[rt][r], mx);
          float al = exp2f(mrow[rt][r] - mnew);
          mrow[rt][r] = mnew;
          alpha[rt][r] = al;
          float rs = 0.f;
#pragma unroll
          for (int ct = 0; ct < 4; ct++) {
            float p = exp2f(s[rt][ct][r] - mnew);
            s[rt][ct][r] = p;
            rs += p;
          }
          rs += __shfl_xor(rs, 1);
          rs += __shfl_xor(rs, 2);
          rs += __shfl_xor(rs, 4);
          rs += __shfl_xor(rs, 8);
          lsum[rt][r] = lsum[rt][r] * al + rs;
        }

      // rescale O accumulator
#pragma unroll
      for (int rt = 0; rt < 2; rt++)
#pragma unroll
        for (int dt = 0; dt < 8; dt++)
#pragma unroll
          for (int r = 0; r < 4; r++) oacc[rt][dt][r] *= alpha[rt][r];

      // P: C-layout regs -> LDS -> A-operand fragments (m120 pattern)
#pragma unroll
      for (int rt = 0; rt < 2; rt++)
#pragma unroll
        for (int ct = 0; ct < 4; ct++)
#pragma unroll
          for (int r = 0; r < 4; r++)
            Ps[w][(rt * 16 + lh * 4 + r) * 72 + ct * 16 + lr] = (bf16)s[rt][ct][r];
      bf16x8 pf[2][2];
#pragma unroll
      for (int rt = 0; rt < 2; rt++)
#pragma unroll
        for (int ks = 0; ks < 2; ks++)
          pf[rt][ks] = *(const bf16x8*)&Ps[w][(rt * 16 + lr) * 72 + ks * 32 + lh * 8];

      // O += P V  (B-operand from swizzled Vts: row = d, k-contiguous kpos)
#pragma unroll
      for (int dt = 0; dt < 8; dt++)
#pragma unroll
        for (int ks = 0; ks < 2; ks++) {
          bf16x8 vf = *(const bf16x8*)&Vts[((dt * 16 + lr) * 8 +
                                            ((ks * 4 + lh) ^ (lr & 7))) * 8];
#pragma unroll
          for (int rt = 0; rt < 2; rt++)
            oacc[rt][dt] =
                __builtin_amdgcn_mfma_f32_16x16x32_bf16(pf[rt][ks], vf, oacc[rt][dt], 0, 0, 0);
        }
    }

    // epilogue: normalize and store
#pragma unroll
    for (int rt = 0; rt < 2; rt++)
#pragma unroll
      for (int dt = 0; dt < 8; dt++)
#pragma unroll
        for (int r = 0; r < 4; r++) {
          float o = oacc[rt][dt][r] / lsum[rt][r];
          int row = b * 2048 + qrow0 + rt * 16 + lh * 4 + r;
          int col = h * 128 + dt * 16 + lr;
          ao[(size_t)row * 4096 + col] = (bf16)o;
        }
  }
}

extern "C" void kernel_launch(void* const* d_in, const int* in_sizes, int n_in,
                              void* d_out, int out_size, void* d_ws, size_t ws_size,
                              hipStream_t stream) {
  const float* x = (const float*)d_in[0];
  const float* wq = (const float*)d_in[1];
  const float* wk = (const float*)d_in[2];
  const float* wv = (const float*)d_in[3];
  const float* wo = (const float*)d_in[4];
  float* out = (float*)d_out;

  char* ws = (char*)d_ws;
  bf16* xb = (bf16*)(ws + 0);
  bf16* wt = (bf16*)(ws + 33554432);       // [6144][4096]: wq^T | wk^T | wv^T
  bf16* wot = (bf16*)(ws + 83886080);      // [4096][4096]
  bf16* qkv = (bf16*)(ws + 117440512);     // [4096][6144]
  bf16* vt = (bf16*)(ws + 167772160);      // [16][128][2048]
  bf16* ao = (bf16*)(ws + 176160768);      // [4096][4096]
  if (ws_size < 209715200u) return;        // need ~210MB scratch

  // 1/sqrt(128) * log2(e): softmax runs natively in exp2 domain
  const float qscale = 0.08838834764831845f * 1.4426950408889634f;

  cast_f32_bf16<<<8192, 256, 0, stream>>>(x, xb, 16777216);
  dim3 tb(32, 8);
  transpose_cast_w<<<dim3(128, 128), tb, 0, stream>>>(wq, wt, 4096, 4096, qscale);
  transpose_cast_w<<<dim3(32, 128), tb, 0, stream>>>(wk, wt + (size_t)4096 * 4096,
                                                     4096, 1024, 1.0f);
  transpose_cast_w<<<dim3(32, 128), tb, 0, stream>>>(wv, wt + (size_t)5120 * 4096,
                                                     4096, 1024, 1.0f);
  transpose_cast_w<<<dim3(128, 128), tb, 0, stream>>>(wo, wot, 4096, 4096, 1.0f);

  gemm_bt<bf16><<<dim3(48, 32), 256, 0, stream>>>(xb, wt, qkv, 4096, 6144, 4096);
  transpose_v<<<dim3(64, 4, 16), tb, 0, stream>>>(qkv, vt);
  flash_attn<<<dim3(8, 32, 2), 256, 0, stream>>>(qkv, vt, ao);
  gemm_bt<float><<<dim3(32, 32), 256, 0, stream>>>(ao, wot, out, 4096, 4096, 4096);
}

// Round 3
// 814.810 us; speedup vs baseline: 1.2452x; 1.0019x over previous
//
#include <hip/hip_runtime.h>
#include <cstdint>

// SelfAttention fused pipeline, bf16 MFMA path.
// B=2 S=2048 DIM=4096 HQ=32 HKV=8 D=128, causal, start_pos=0.
//
// R2 changes:
//  - gemm_bt: XOR-swizzle As/Bs 16B-chunk placement (DMA source side).
//    Row stride 64B aliased the 16 lr-lanes of each fragment read onto 2 bank
//    quads (8-way conflict, 2.94x); swizzle chunk' = j ^ ((row>>1)&3) spreads
//    them over all 8 quads (2-way = free). Read-side term is lane-constant:
//    lh ^ ((lr>>1)&3).
//  - merged the 4 weight transpose launches into one kernel.
//
// ws layout (bytes):
//   xb    @ 0         : bf16[4096][4096]   x cast               (33.5 MB)
//   wt    @ 33554432  : bf16[6144][4096]   [wq^T*scale; wk^T; wv^T] (50.3 MB)
//   wot   @ 83886080  : bf16[4096][4096]   wo^T                 (33.5 MB)
//   qkv   @ 117440512 : bf16[4096][6144]   x@[wq wk wv]         (50.3 MB)
//   vt    @ 167772160 : bf16[2][8][128][2048] V^T per kv head   (8.4 MB)
//   ao    @ 176160768 : bf16[4096][4096]   attention output     (33.5 MB)
// total 209715200 bytes.

typedef __bf16 bf16;
typedef __bf16 bf16x8 __attribute__((ext_vector_type(8)));
typedef float f32x4 __attribute__((ext_vector_type(4)));

#define DEV_INLINE __device__ __forceinline__

DEV_INLINE void load_lds16(const bf16* g, bf16* l) {
  // async global->LDS, 16B per lane; LDS dest = wave-uniform base + lane*16
  __builtin_amdgcn_global_load_lds(
      (const __attribute__((address_space(1))) void*)g,
      (__attribute__((address_space(3))) void*)l, 16, 0, 0);
}

// ---------------- elementwise cast f32 -> bf16, 8 elems/thread ----------------
__global__ __launch_bounds__(256) void cast_f32_bf16(const float* __restrict__ in,
                                                     bf16* __restrict__ out, int n) {
  int i = (blockIdx.x * 256 + threadIdx.x) * 8;
  if (i >= n) return;
  float4 a = *(const float4*)(in + i);
  float4 b = *(const float4*)(in + i + 4);
  bf16x8 o;
  o[0] = (bf16)a.x; o[1] = (bf16)a.y; o[2] = (bf16)a.z; o[3] = (bf16)a.w;
  o[4] = (bf16)b.x; o[5] = (bf16)b.y; o[6] = (bf16)b.z; o[7] = (bf16)b.w;
  *(bf16x8*)(out + i) = o;
}

// --- merged transpose+cast of all 4 weights: f32 [K=4096][N] -> bf16 [N][4096]
// x-blocks 0..127 -> wq (scale), 128..159 -> wk, 160..191 -> wv, 192..319 -> wo
__global__ __launch_bounds__(256) void transpose_cast_all(
    const float* __restrict__ wq, const float* __restrict__ wk,
    const float* __restrict__ wv, const float* __restrict__ wo,
    bf16* __restrict__ wt, bf16* __restrict__ wot, float qscale) {
  __shared__ float t[32][33];
  int bx = blockIdx.x, k0 = blockIdx.y * 32;
  const float* src;
  bf16* dst;
  int N, ncol0, nrow0;
  float scale = 1.0f;
  if (bx < 128) {        // wq -> wt rows [0,4096)
    src = wq; dst = wt; N = 4096; ncol0 = bx * 32; nrow0 = ncol0; scale = qscale;
  } else if (bx < 160) { // wk -> wt rows [4096,5120)
    src = wk; dst = wt; N = 1024; ncol0 = (bx - 128) * 32; nrow0 = 4096 + ncol0;
  } else if (bx < 192) { // wv -> wt rows [5120,6144)
    src = wv; dst = wt; N = 1024; ncol0 = (bx - 160) * 32; nrow0 = 5120 + ncol0;
  } else {               // wo -> wot
    src = wo; dst = wot; N = 4096; ncol0 = (bx - 192) * 32; nrow0 = ncol0;
  }
  int tx = threadIdx.x, ty = threadIdx.y;
#pragma unroll
  for (int i = 0; i < 32; i += 8)
    t[ty + i][tx] = src[(size_t)(k0 + ty + i) * N + ncol0 + tx];
  __syncthreads();
#pragma unroll
  for (int i = 0; i < 32; i += 8)
    dst[(size_t)(nrow0 + ty + i) * 4096 + k0 + tx] = (bf16)(t[tx][ty + i] * scale);
}

// ------ transpose V slice of qkv[4096][6144] -> vt[(b*8+h)*128 + d][2048] -----
__global__ __launch_bounds__(256) void transpose_v(const bf16* __restrict__ qkv,
                                                   bf16* __restrict__ vt) {
  __shared__ bf16 t[32][33];
  int s0 = blockIdx.x * 32, d0 = blockIdx.y * 32, bh = blockIdx.z;
  int b = bh >> 3, h = bh & 7;
  int tx = threadIdx.x, ty = threadIdx.y;
#pragma unroll
  for (int i = 0; i < 32; i += 8)
    t[ty + i][tx] =
        qkv[(size_t)(b * 2048 + s0 + ty + i) * 6144 + 5120 + h * 128 + d0 + tx];
  __syncthreads();
#pragma unroll
  for (int i = 0; i < 32; i += 8)
    vt[((size_t)bh * 128 + d0 + ty + i) * 2048 + s0 + tx] = t[tx][ty + i];
}

// --------- m97-style GEMM: C[M][N] = A[M][K] * Bt[N][K]^T, bf16 MFMA ---------
// LDS tiles 128 rows x 32 els (4 x 16B chunks/row), XOR-swizzled:
//   physical chunk row*4 + x holds logical chunk x ^ ((row>>1)&3).
template <typename OT>
__global__ __launch_bounds__(256, 2) void gemm_bt(const bf16* __restrict__ A,
                                                  const bf16* __restrict__ Bt,
                                                  OT* __restrict__ C,
                                                  int M, int N, int K) {
  __shared__ __align__(16) bf16 As[128 * 32];
  __shared__ __align__(16) bf16 Bs[128 * 32];
  const int t = threadIdx.x, w = t >> 6, l = t & 63;
  const int lr = l & 15, lh = l >> 4;
  const int mBase = blockIdx.y * 128, nBase = blockIdx.x * 128;
  const int wm = (w >> 1) * 64, wn = (w & 1) * 64;
  // read-side swizzle: row = (mult of 16) + lr -> (row>>1)&3 == (lr>>1)&3
  const int swz = (lh ^ ((lr >> 1) & 3)) * 8;
  f32x4 acc[4][4] = {};
  for (int k0 = 0; k0 < K; k0 += 32) {
#pragma unroll
    for (int p = 0; p < 2; p++) {
      int c = p * 256 + t;               // physical 16B chunk id, 512 per tile
      int row = c >> 2;
      int kq = (c & 3) ^ ((c >> 3) & 3);  // logical chunk stored at c
      int ldsoff = (p * 256 + w * 64) * 8;  // elements; hw adds lane*16B
      load_lds16(A + (size_t)(mBase + row) * K + k0 + kq * 8, &As[ldsoff]);
      load_lds16(Bt + (size_t)(nBase + row) * K + k0 + kq * 8, &Bs[ldsoff]);
    }
    __syncthreads();
    bf16x8 a[4], b[4];
#pragma unroll
    for (int mi = 0; mi < 4; mi++)
      a[mi] = *(const bf16x8*)&As[(wm + mi * 16 + lr) * 32 + swz];
#pragma unroll
    for (int ni = 0; ni < 4; ni++)
      b[ni] = *(const bf16x8*)&Bs[(wn + ni * 16 + lr) * 32 + swz];
#pragma unroll
    for (int mi = 0; mi < 4; mi++)
#pragma unroll
      for (int ni = 0; ni < 4; ni++)
        acc[mi][ni] = __builtin_amdgcn_mfma_f32_16x16x32_bf16(a[mi], b[ni],
                                                              acc[mi][ni], 0, 0, 0);
    __syncthreads();
  }
#pragma unroll
  for (int mi = 0; mi < 4; mi++)
#pragma unroll
    for (int ni = 0; ni < 4; ni++) {
      int row = mBase + wm + mi * 16 + lh * 4;
      int col = nBase + wn + ni * 16 + lr;
#pragma unroll
      for (int r = 0; r < 4; r++)
        C[(size_t)(row + r) * N + col] = (OT)acc[mi][ni][r];
    }
}

// ------------------------------ flash attention ------------------------------
// grid (8, h=32, b=2), block 256. Block handles q-tiles blockIdx.x and
// 15-blockIdx.x -> uniform 34 k-tiles/block. Wave w: q rows [qt*128+w*32,+32).
// KTILE=64. Ks[k][d] / Vts[d][kpos] stored with XOR-swizzled 16B chunks:
//   Ks  chunk(k, j)  at physical chunk k*16 + (j ^ (k & 15))   (16 chunks/row)
//   Vts chunk(d, j)  at physical chunk d*8  + (j ^ (d & 7))    (8 chunks/row)
// -> row-strided b128 reads spread over all bank quads (2-way max = free).
// Softmax in base-2 domain (log2e folded into wq scale).
__global__ __launch_bounds__(256, 2) void flash_attn(const bf16* __restrict__ qkv,
                                                     const bf16* __restrict__ vt,
                                                     bf16* __restrict__ ao) {
  __shared__ __align__(16) bf16 Ks[64 * 128];
  __shared__ __align__(16) bf16 Vts[128 * 64];
  __shared__ __align__(16) bf16 Ps[4][32 * 72];
  const int t = threadIdx.x, w = t >> 6, l = t & 63;
  const int lr = l & 15, lh = l >> 4;
  const int h = blockIdx.y, b = blockIdx.z;
  const int hkv = h >> 2;                 // jnp.repeat: q head h <- kv head h/4

  for (int phase = 0; phase < 2; phase++) {
    const int qt = phase == 0 ? blockIdx.x : 15 - blockIdx.x;
    const int qrow0 = qt * 128 + w * 32;

    // Q fragments (A-operand): q = qrow0 + rt*16 + lr, d = ds*32 + lh*8 + j.
    // log2(e)/sqrt(128) already folded into wq.
    bf16x8 qf[2][4];
#pragma unroll
    for (int rt = 0; rt < 2; rt++)
#pragma unroll
      for (int ds = 0; ds < 4; ds++)
        qf[rt][ds] = *(const bf16x8*)&qkv[(size_t)(b * 2048 + qrow0 + rt * 16 + lr) * 6144 +
                                          h * 128 + ds * 32 + lh * 8];

    f32x4 oacc[2][8] = {};
    float mrow[2][4], lsum[2][4];
#pragma unroll
    for (int rt = 0; rt < 2; rt++)
#pragma unroll
      for (int r = 0; r < 4; r++) { mrow[rt][r] = -3.0e38f; lsum[rt][r] = 0.f; }

    const int nkt = 2 * qt + 2;
    for (int kt = 0; kt < nkt; kt++) {
      const int kbase = kt * 64;
      __syncthreads();  // prior iteration's (or phase's) LDS reads complete
#pragma unroll
      for (int p = 0; p < 4; p++) {
        int c = p * 256 + t;
        int ldsoff = (p * 256 + w * 64) * 8;
        // Ks: physical chunk c holds logical chunk (c&15)^(krow&15) of row c>>4
        int krow = c >> 4, kj = (c & 15) ^ (krow & 15);
        load_lds16(qkv + (size_t)(b * 2048 + kbase + krow) * 6144 + 4096 +
                       hkv * 128 + kj * 8,
                   &Ks[ldsoff]);
        // Vts: physical chunk c holds logical chunk (c&7)^(vrow&7) of row c>>3
        int vrow = c >> 3, vj = (c & 7) ^ (vrow & 7);
        load_lds16(vt + ((size_t)(b * 8 + hkv) * 128 + vrow) * 2048 + kbase +
                       vj * 8,
                   &Vts[ldsoff]);
      }
      __syncthreads();

      // S = Q K^T  (C/D layout: row = rt*16 + lh*4 + r, col = ct*16 + lr)
      f32x4 s[2][4];
#pragma unroll
      for (int ct = 0; ct < 4; ct++) {
        bf16x8 kf[4];
#pragma unroll
        for (int ds = 0; ds < 4; ds++)
          kf[ds] = *(const bf16x8*)&Ks[((ct * 16 + lr) * 16 + ((ds * 4 + lh) ^ lr)) * 8];
#pragma unroll
        for (int rt = 0; rt < 2; rt++) {
          f32x4 acc = {0.f, 0.f, 0.f, 0.f};
#pragma unroll
          for (int ds = 0; ds < 4; ds++)
            acc = __builtin_amdgcn_mfma_f32_16x16x32_bf16(qf[rt][ds], kf[ds], acc, 0, 0, 0);
          s[rt][ct] = acc;
        }
      }

      if (kt >= 2 * qt) {  // diagonal tiles only
#pragma unroll
        for (int rt = 0; rt < 2; rt++)
#pragma unroll
          for (int ct = 0; ct < 4; ct++)
#pragma unroll
            for (int r = 0; r < 4; r++) {
              int qi = qrow0 + rt * 16 + lh * 4 + r;
              int ki = kbase + ct * 16 + lr;
              if (ki > qi) s[rt][ct][r] = -3.0e38f;
            }
      }

      // online softmax (base-2 domain), rows per lane: (rt, r), 16-lane groups
      float alpha[2][4];
#pragma unroll
      for (int rt = 0; rt < 2; rt++)
#pragma unroll
        for (int r = 0; r < 4; r++) {
          float mx = fmaxf(fmaxf(s[rt][0][r], s[rt][1][r]),
                           fmaxf(s[rt][2][r], s[rt][3][r]));
          mx = fmaxf(mx, __shfl_xor(mx, 1));
          mx = fmaxf(mx, __shfl_xor(mx, 2));
          mx = fmaxf(mx, __shfl_xor(mx, 4));
          mx = fmaxf(mx, __shfl_xor(mx, 8));
          float mnew = fmaxf(mrow[rt][r], mx);
          float al = exp2f(mrow[rt][r] - mnew);
          mrow[rt][r] = mnew;
          alpha[rt][r] = al;
          float rs = 0.f;
#pragma unroll
          for (int ct = 0; ct < 4; ct++) {
            float p = exp2f(s[rt][ct][r] - mnew);
            s[rt][ct][r] = p;
            rs += p;
          }
          rs += __shfl_xor(rs, 1);
          rs += __shfl_xor(rs, 2);
          rs += __shfl_xor(rs, 4);
          rs += __shfl_xor(rs, 8);
          lsum[rt][r] = lsum[rt][r] * al + rs;
        }

      // rescale O accumulator
#pragma unroll
      for (int rt = 0; rt < 2; rt++)
#pragma unroll
        for (int dt = 0; dt < 8; dt++)
#pragma unroll
          for (int r = 0; r < 4; r++) oacc[rt][dt][r] *= alpha[rt][r];

      // P: C-layout regs -> LDS -> A-operand fragments (m120 pattern)
#pragma unroll
      for (int rt = 0; rt < 2; rt++)
#pragma unroll
        for (int ct = 0; ct < 4; ct++)
#pragma unroll
          for (int r = 0; r < 4; r++)
            Ps[w][(rt * 16 + lh * 4 + r) * 72 + ct * 16 + lr] = (bf16)s[rt][ct][r];
      bf16x8 pf[2][2];
#pragma unroll
      for (int rt = 0; rt < 2; rt++)
#pragma unroll
        for (int ks = 0; ks < 2; ks++)
          pf[rt][ks] = *(const bf16x8*)&Ps[w][(rt * 16 + lr) * 72 + ks * 32 + lh * 8];

      // O += P V  (B-operand from swizzled Vts: row = d, k-contiguous kpos)
#pragma unroll
      for (int dt = 0; dt < 8; dt++)
#pragma unroll
        for (int ks = 0; ks < 2; ks++) {
          bf16x8 vf = *(const bf16x8*)&Vts[((dt * 16 + lr) * 8 +
                                            ((ks * 4 + lh) ^ (lr & 7))) * 8];
#pragma unroll
          for (int rt = 0; rt < 2; rt++)
            oacc[rt][dt] =
                __builtin_amdgcn_mfma_f32_16x16x32_bf16(pf[rt][ks], vf, oacc[rt][dt], 0, 0, 0);
        }
    }

    // epilogue: normalize and store
#pragma unroll
    for (int rt = 0; rt < 2; rt++)
#pragma unroll
      for (int dt = 0; dt < 8; dt++)
#pragma unroll
        for (int r = 0; r < 4; r++) {
          float o = oacc[rt][dt][r] / lsum[rt][r];
          int row = b * 2048 + qrow0 + rt * 16 + lh * 4 + r;
          int col = h * 128 + dt * 16 + lr;
          ao[(size_t)row * 4096 + col] = (bf16)o;
        }
  }
}

extern "C" void kernel_launch(void* const* d_in, const int* in_sizes, int n_in,
                              void* d_out, int out_size, void* d_ws, size_t ws_size,
                              hipStream_t stream) {
  const float* x = (const float*)d_in[0];
  const float* wq = (const float*)d_in[1];
  const float* wk = (const float*)d_in[2];
  const float* wv = (const float*)d_in[3];
  const float* wo = (const float*)d_in[4];
  float* out = (float*)d_out;

  char* ws = (char*)d_ws;
  bf16* xb = (bf16*)(ws + 0);
  bf16* wt = (bf16*)(ws + 33554432);       // [6144][4096]: wq^T | wk^T | wv^T
  bf16* wot = (bf16*)(ws + 83886080);      // [4096][4096]
  bf16* qkv = (bf16*)(ws + 117440512);     // [4096][6144]
  bf16* vt = (bf16*)(ws + 167772160);      // [16][128][2048]
  bf16* ao = (bf16*)(ws + 176160768);      // [4096][4096]
  if (ws_size < 209715200u) return;        // need ~210MB scratch

  // 1/sqrt(128) * log2(e): softmax runs natively in exp2 domain
  const float qscale = 0.08838834764831845f * 1.4426950408889634f;

  cast_f32_bf16<<<8192, 256, 0, stream>>>(x, xb, 16777216);
  transpose_cast_all<<<dim3(320, 128), dim3(32, 8), 0, stream>>>(
      wq, wk, wv, wo, wt, wot, qscale);

  gemm_bt<bf16><<<dim3(48, 32), 256, 0, stream>>>(xb, wt, qkv, 4096, 6144, 4096);
  transpose_v<<<dim3(64, 4, 16), dim3(32, 8), 0, stream>>>(qkv, vt);
  flash_attn<<<dim3(8, 32, 2), 256, 0, stream>>>(qkv, vt, ao);
  gemm_bt<float><<<dim3(32, 32), 256, 0, stream>>>(ao, wot, out, 4096, 4096, 4096);
}